// Round 10
// baseline (670.998 us; speedup 1.0000x reference)
//
#include <hip/hip_runtime.h>
#include <hip/hip_bf16.h>
#include <stdint.h>

#define BATCH 8192
#define IN_F  4096
#define OUT_F 4096
#define NFRAG 32
#define FSIZE 128
#define COMP  512
#define KCAT  4608   // IN_F + COMP

typedef float f32x4 __attribute__((ext_vector_type(4)));
typedef short bf16x8 __attribute__((ext_vector_type(8)));

__device__ __forceinline__ unsigned short f2bf(float f) {
  union { float f; unsigned u; } v; v.f = f;
  return (unsigned short)((v.u + 0x7FFFu + ((v.u >> 16) & 1u)) >> 16);
}
__device__ __forceinline__ unsigned pack2(float a, float b) {
  return (unsigned)f2bf(a) | ((unsigned)f2bf(b) << 16);
}

typedef const __attribute__((address_space(1))) unsigned* as1_u32p;
typedef __attribute__((address_space(3))) unsigned* as3_u32p;

__device__ __forceinline__ void lds_load16(const void* g, void* l) {
  __builtin_amdgcn_global_load_lds((as1_u32p)(uintptr_t)g, (as3_u32p)(uintptr_t)l, 16, 0, 0);
}

// ---------------- routing: probs + scaled bf16 copies ----------------
__global__ __launch_bounds__(256) void k_route(
    const float* __restrict__ x, const float* __restrict__ sel,
    unsigned short* __restrict__ xw, unsigned short* __restrict__ xm) {
  __shared__ float red[256];
  __shared__ float sc[NFRAG];
  const int b = blockIdx.x;
  const int t = threadIdx.x;
  const float* xr = x + (size_t)b * IN_F;
  const int frag = t >> 3;

  float4 v0 = *(const float4*)&xr[t * 16 + 0];
  float4 v1 = *(const float4*)&xr[t * 16 + 4];
  float4 v2 = *(const float4*)&xr[t * 16 + 8];
  float4 v3 = *(const float4*)&xr[t * 16 + 12];
  const float* sw = sel + frag * FSIZE + (t & 7) * 16;
  float4 s0 = *(const float4*)&sw[0];
  float4 s1 = *(const float4*)&sw[4];
  float4 s2 = *(const float4*)&sw[8];
  float4 s3 = *(const float4*)&sw[12];
  float d = v0.x*s0.x + v0.y*s0.y + v0.z*s0.z + v0.w*s0.w
          + v1.x*s1.x + v1.y*s1.y + v1.z*s1.z + v1.w*s1.w
          + v2.x*s2.x + v2.y*s2.y + v2.z*s2.z + v2.w*s2.w
          + v3.x*s3.x + v3.y*s3.y + v3.z*s3.z + v3.w*s3.w;
  red[t] = d;
  __syncthreads();
  if (t < NFRAG) {
    float s = 0.f;
#pragma unroll
    for (int j = 0; j < 8; ++j) s += red[t * 8 + j];
    sc[t] = s;
  }
  __syncthreads();
  float mx = sc[0];
#pragma unroll
  for (int f = 1; f < NFRAG; ++f) mx = fmaxf(mx, sc[f]);
  float den = 0.f;
#pragma unroll
  for (int f = 0; f < NFRAG; ++f) den += __expf(sc[f] - mx);
  const float p = __expf(sc[frag] - mx) / den;
  const float q = 1.f - p;

  const size_t bw = (size_t)b * KCAT + (size_t)t * 16;
  const size_t bm_ = (size_t)b * IN_F + (size_t)t * 16;
  uint4 w;
  w.x = pack2(v0.x*p, v0.y*p); w.y = pack2(v0.z*p, v0.w*p);
  w.z = pack2(v1.x*p, v1.y*p); w.w = pack2(v1.z*p, v1.w*p);
  *(uint4*)&xw[bw] = w;
  w.x = pack2(v2.x*p, v2.y*p); w.y = pack2(v2.z*p, v2.w*p);
  w.z = pack2(v3.x*p, v3.y*p); w.w = pack2(v3.z*p, v3.w*p);
  *(uint4*)&xw[bw + 8] = w;
  w.x = pack2(v0.x*q, v0.y*q); w.y = pack2(v0.z*q, v0.w*q);
  w.z = pack2(v1.x*q, v1.y*q); w.w = pack2(v1.z*q, v1.w*q);
  *(uint4*)&xm[bm_] = w;
  w.x = pack2(v2.x*q, v2.y*q); w.y = pack2(v2.z*q, v2.w*q);
  w.z = pack2(v3.x*q, v3.y*q); w.w = pack2(v3.z*q, v3.w*q);
  *(uint4*)&xm[bm_ + 8] = w;
}

// ---------------- f32 [R][C] -> bf16 [C][R] transpose-convert, strided dst ----------------
__global__ __launch_bounds__(256) void k_transpose_bf16(
    const float* __restrict__ src, unsigned short* __restrict__ dst,
    int R, int C, int ldd) {
  __shared__ float tile[64][65];
  const int t = threadIdx.x;
  const int c0 = blockIdx.x * 64, r0 = blockIdx.y * 64;
#pragma unroll
  for (int i = 0; i < 4; ++i) {
    const int q = i * 256 + t;
    const int row = q >> 4;
    const int col = (q & 15) << 2;
    float4 v = *(const float4*)&src[(size_t)(r0 + row) * C + c0 + col];
    tile[row][col + 0] = v.x; tile[row][col + 1] = v.y;
    tile[row][col + 2] = v.z; tile[row][col + 3] = v.w;
  }
  __syncthreads();
#pragma unroll
  for (int i = 0; i < 4; ++i) {
    const int q = i * 256 + t;
    const int orow = q >> 4;
    const int oc = (q & 15) << 2;
    ushort4 o;
    o.x = f2bf(tile[oc + 0][orow]);
    o.y = f2bf(tile[oc + 1][orow]);
    o.z = f2bf(tile[oc + 2][orow]);
    o.w = f2bf(tile[oc + 3][orow]);
    *(ushort4*)&dst[(size_t)(c0 + orow) * ldd + r0 + oc] = o;
  }
}

// ---------------- 128^2 bf16 GEMM (m97 structure) — G2 (N=512) ----------------
#define BM 128
#define BN 128
#define BK 64

template <int EPI>
__global__ __launch_bounds__(256) void k_gemm_bt(
    const unsigned short* __restrict__ A, int lda,
    const unsigned short* __restrict__ Bt, int ldb,
    void* __restrict__ Cp, int ldc, int M, int N, int K) {
  __shared__ unsigned short lA[BM * BK];
  __shared__ unsigned short lB[BN * BK];
  const int t = threadIdx.x;
  const int lane = t & 63;
  const int wave = t >> 6;
  const int wr = wave >> 1, wc = wave & 1;
  const int hi = lane >> 4, lo = lane & 15;
  const int bm = blockIdx.y * BM, bn = blockIdx.x * BN;

  f32x4 acc[4][4] = {};

  for (int kt = 0; kt < K; kt += BK) {
#pragma unroll
    for (int i = 0; i < 4; ++i) {
      const int c = i * 256 + t;
      const int row = c >> 3, cc = c & 7;
      lds_load16(&A [(size_t)(bm + row) * lda + kt + cc * 8], (char*)lA + c * 16);
      lds_load16(&Bt[(size_t)(bn + row) * ldb + kt + cc * 8], (char*)lB + c * 16);
    }
    __syncthreads();
#pragma unroll
    for (int kk = 0; kk < BK; kk += 32) {
      bf16x8 af[4], bfr[4];
#pragma unroll
      for (int m = 0; m < 4; ++m)
        af[m] = *(const bf16x8*)&lA[(wr * 64 + m * 16 + lo) * BK + kk + hi * 8];
#pragma unroll
      for (int n = 0; n < 4; ++n)
        bfr[n] = *(const bf16x8*)&lB[(wc * 64 + n * 16 + lo) * BK + kk + hi * 8];
#pragma unroll
      for (int m = 0; m < 4; ++m)
#pragma unroll
        for (int n = 0; n < 4; ++n)
          acc[m][n] = __builtin_amdgcn_mfma_f32_16x16x32_bf16(af[m], bfr[n], acc[m][n], 0, 0, 0);
    }
    __syncthreads();
  }

  float* Cf = (float*)Cp;
  unsigned short* Cb = (unsigned short*)Cp;
#pragma unroll
  for (int m = 0; m < 4; ++m)
#pragma unroll
    for (int n = 0; n < 4; ++n)
#pragma unroll
      for (int r = 0; r < 4; ++r) {
        const int row = bm + wr * 64 + m * 16 + hi * 4 + r;
        const int col = bn + wc * 64 + n * 16 + lo;
        const size_t idx = (size_t)row * ldc + col;
        if constexpr (EPI == 0)      Cf[idx] = acc[m][n][r];
        else if constexpr (EPI == 1) Cf[idx] += acc[m][n][r];
        else                         Cb[idx] = f2bf(acc[m][n][r]);
      }
}

// ---------------- 256^2 bf16 GEMM: ring-4 K32 tiles + register-frag double-buffer ----------------
// Iter tt: {ds_read tile tt+1 -> nxt regs | STAGE tile tt+3 | lgkmcnt(12) (cur regs ready,
// nxt still in flight) | 32 MFMA on cur | vmcnt(4) (tile tt+2 landed, tt+3 in flight) |
// s_barrier}. MFMA never waits on freshly-issued reads; lgkm/vmcnt both counted (T4/T14).
// Swizzle identical to the verified R6 kernel (conflict-free, both-sides).
#define G_SLOT  16384
#define G_STRIDE 32768
#define G_LDS   131072   // 4 ring slots

__global__ __launch_bounds__(512, 2) void k_gemm256(
    const unsigned short* __restrict__ A, int lda,
    const unsigned short* __restrict__ Bt, int ldb,
    float* __restrict__ C, int M, int N, int K) {
  extern __shared__ char lds[];
  const int t = threadIdx.x;
  const int lane = t & 63;
  const int wid = t >> 6;
  const int wr = wid >> 2;
  const int wc = wid & 3;
  const int lo = lane & 15, hi = lane >> 4;

  const int nwg = gridDim.x;
  const int chunk = nwg >> 3;
  const int remap = ((int)blockIdx.x & 7) * chunk + ((int)blockIdx.x >> 3);
  const int nx = N >> 8;
  const int bm = (remap / nx) << 8;
  const int bn = (remap % nx) << 8;

  const int NT = K >> 5;

  const int c0 = t,       r0 = c0 >> 2, s0 = (c0 & 3) ^ ((r0 >> 1) & 3);
  const int c1 = t + 512, r1 = c1 >> 2, s1 = (c1 & 3) ^ ((r1 >> 1) & 3);
  const unsigned short* Ap0 = A  + (size_t)(bm + r0) * lda + s0 * 8;
  const unsigned short* Ap1 = A  + (size_t)(bm + r1) * lda + s1 * 8;
  const unsigned short* Bp0 = Bt + (size_t)(bn + r0) * ldb + s0 * 8;
  const unsigned short* Bp1 = Bt + (size_t)(bn + r1) * ldb + s1 * 8;

  const int ksl = ((hi ^ ((lo >> 1) & 3)) << 4);
  const int aBase = wr * 8192 + lo * 64 + ksl;            // + m*1024
  const int bBase = G_SLOT + wc * 4096 + lo * 64 + ksl;   // + n*1024

  f32x4 acc[8][4] = {};
  bf16x8 aR0[8], bR0[4], aR1[8], bR1[4];

#define STAGE(tt_) do {                                            \
    char* _b = lds + ((tt_) & 3) * G_STRIDE;                       \
    const int _kt = (tt_) << 5;                                    \
    lds_load16(Ap0 + _kt, _b + c0 * 16);                           \
    lds_load16(Ap1 + _kt, _b + c1 * 16);                           \
    lds_load16(Bp0 + _kt, _b + G_SLOT + c0 * 16);                  \
    lds_load16(Bp1 + _kt, _b + G_SLOT + c1 * 16);                  \
  } while (0)

#define LOADFRAGS(da, db, tt_) do {                                \
    const char* _s = lds + ((tt_) & 3) * G_STRIDE;                 \
    _Pragma("unroll")                                              \
    for (int n = 0; n < 4; ++n) db[n] = *(const bf16x8*)(_s + bBase + n * 1024); \
    _Pragma("unroll")                                              \
    for (int m = 0; m < 8; ++m) da[m] = *(const bf16x8*)(_s + aBase + m * 1024); \
  } while (0)

#define MFMAS(sa_, sb_) do {                                       \
    _Pragma("unroll")                                              \
    for (int m = 0; m < 8; ++m)                                    \
      _Pragma("unroll")                                            \
      for (int n = 0; n < 4; ++n)                                  \
        acc[m][n] = __builtin_amdgcn_mfma_f32_16x16x32_bf16(sa_[m], sb_[n], acc[m][n], 0, 0, 0); \
  } while (0)

  // prologue: 3 tiles in flight; tiles 0,1 landed after vmcnt(4)
  STAGE(0); STAGE(1); STAGE(2);
  asm volatile("s_waitcnt vmcnt(4)" ::: "memory");
  __builtin_amdgcn_sched_barrier(0);
  __builtin_amdgcn_s_barrier();
  __builtin_amdgcn_sched_barrier(0);
  LOADFRAGS(aR0, bR0, 0);

  for (int tt = 0; tt < NT; tt += 2) {
    // -------- even half: compute tile tt from (aR0,bR0), prefetch tile tt+1 --------
    if (tt + 1 < NT) LOADFRAGS(aR1, bR1, tt + 1);
    if (tt + 3 < NT) STAGE(tt + 3);
    if (tt + 1 < NT) { asm volatile("s_waitcnt lgkmcnt(12)" ::: "memory"); }
    else             { asm volatile("s_waitcnt lgkmcnt(0)"  ::: "memory"); }
    __builtin_amdgcn_sched_barrier(0);
    __builtin_amdgcn_s_setprio(1);
    MFMAS(aR0, bR0);
    __builtin_amdgcn_s_setprio(0);
    if (tt + 3 < NT)      { asm volatile("s_waitcnt vmcnt(4)" ::: "memory"); }
    else if (tt + 2 < NT) { asm volatile("s_waitcnt vmcnt(0)" ::: "memory"); }
    __builtin_amdgcn_sched_barrier(0);
    __builtin_amdgcn_s_barrier();
    __builtin_amdgcn_sched_barrier(0);

    // -------- odd half: compute tile tt+1 from (aR1,bR1), prefetch tile tt+2 --------
    if (tt + 1 < NT) {
      if (tt + 2 < NT) LOADFRAGS(aR0, bR0, tt + 2);
      if (tt + 4 < NT) STAGE(tt + 4);
      if (tt + 2 < NT) { asm volatile("s_waitcnt lgkmcnt(12)" ::: "memory"); }
      else             { asm volatile("s_waitcnt lgkmcnt(0)"  ::: "memory"); }
      __builtin_amdgcn_sched_barrier(0);
      __builtin_amdgcn_s_setprio(1);
      MFMAS(aR1, bR1);
      __builtin_amdgcn_s_setprio(0);
      if (tt + 4 < NT)      { asm volatile("s_waitcnt vmcnt(4)" ::: "memory"); }
      else if (tt + 3 < NT) { asm volatile("s_waitcnt vmcnt(0)" ::: "memory"); }
      __builtin_amdgcn_sched_barrier(0);
      __builtin_amdgcn_s_barrier();
      __builtin_amdgcn_sched_barrier(0);
    }
  }
#undef STAGE
#undef LOADFRAGS
#undef MFMAS

#pragma unroll
  for (int m = 0; m < 8; ++m)
#pragma unroll
    for (int n = 0; n < 4; ++n)
#pragma unroll
      for (int r = 0; r < 4; ++r) {
        const int row = bm + wr * 128 + m * 16 + hi * 4 + r;
        const int col = bn + wc * 64 + n * 16 + lo;
        C[(size_t)row * N + col] = acc[m][n][r];
      }
}

extern "C" void kernel_launch(void* const* d_in, const int* in_sizes, int n_in,
                              void* d_out, int out_size, void* d_ws, size_t ws_size,
                              hipStream_t stream) {
  const float* x   = (const float*)d_in[0];
  const float* sel = (const float*)d_in[1];
  const float* ew  = (const float*)d_in[2];   // [4096 k][4096 o]
  const float* wc1 = (const float*)d_in[3];   // [4096][512]
  const float* wc2 = (const float*)d_in[4];   // [512][4096]
  float* out = (float*)d_out;

  char* ws = (char*)d_ws;
  unsigned short* xcat  = (unsigned short*)(ws);
  unsigned short* xm    = (unsigned short*)(ws + 75497472);
  unsigned short* btcat = (unsigned short*)(ws + 75497472);
  unsigned short* w1ct  = (unsigned short*)(ws + 142606336);

  (void)hipFuncSetAttribute((const void*)k_gemm256,
                            hipFuncAttributeMaxDynamicSharedMemorySize, G_LDS);

  k_route<<<BATCH, 256, 0, stream>>>(x, sel, xcat, xm);
  k_transpose_bf16<<<dim3(COMP / 64, IN_F / 64), 256, 0, stream>>>(wc1, w1ct, IN_F, COMP, IN_F);
  k_gemm_bt<2><<<dim3(COMP / BN, BATCH / BM), 256, 0, stream>>>(
      xm, IN_F, w1ct, IN_F, (void*)(xcat + IN_F), KCAT, BATCH, COMP, IN_F);
  k_transpose_bf16<<<dim3(OUT_F / 64, IN_F / 64), 256, 0, stream>>>(ew, btcat, IN_F, OUT_F, KCAT);
  k_transpose_bf16<<<dim3(OUT_F / 64, COMP / 64), 256, 0, stream>>>(wc2, btcat + IN_F, COMP, OUT_F, KCAT);
  k_gemm256<<<(BATCH / 256) * (OUT_F / 256), 512, G_LDS, stream>>>(
      xcat, KCAT, btcat, KCAT, out, BATCH, OUT_F, KCAT);
}